// Round 3
// baseline (5510.196 us; speedup 1.0000x reference)
//
#include <hip/hip_runtime.h>

#define HIDDEN 51
#define LSEQ 1000
#define NK 26   // k-pairs... k-columns per wave (wave0: k=0..25, wave1: k=26..51 incl zero-pad col 51)

// Branch-free tanh: tanh(v) = 1 - 2/(exp2(2*log2e*v)+1). Saturates to +/-1.
__device__ __forceinline__ float fast_tanh(float v) {
    float e = __builtin_amdgcn_exp2f(v * 2.885390081777927f);  // 2*log2(e)
    float r = __builtin_amdgcn_rcpf(e + 1.0f);
    return fmaf(-2.0f, r, 1.0f);
}

// Two waves per batch element, k-split. Each wave holds 26 columns x 4 gate
// rows of U in VGPRs (104 regs -- fits, no AGPR copy tax). h is broadcast
// through LDS (7 x ds_read_b128 per wave, same-address broadcast) instead of
// 51 v_readlane's. Partial gate sums exchanged via one b128 LDS round-trip;
// both waves redundantly compute the (bitwise-identical) c/h update so the
// recurrent state never crosses waves. 2 waves/SIMD -> stalls of one wave
// are filled by its SIMD sibling. Output dot runs one step behind (butterfly
// hides under the FMA block).
__global__ __launch_bounds__(128, 2) void lstm_seq_kernel(
    const float* __restrict__ x,
    const float* __restrict__ W_w,
    const float* __restrict__ W_b,
    const float* __restrict__ U_w,
    const float* __restrict__ U_b,
    const float* __restrict__ lin_w,
    const float* __restrict__ lin_b,
    float* __restrict__ out)
{
    __shared__ float hb[64];          // h broadcast buffer (h_k at hb[k])
    __shared__ float pg[2][64][4];    // partial gates per wave per lane

    const int b    = blockIdx.x;
    const int tid  = threadIdx.x;
    const int wid  = tid >> 6;         // 0 or 1
    const int lane = tid & 63;
    const bool active = lane < HIDDEN;
    const int m = active ? lane : 0;

    // Per-lane row weights (x-projection + fused bias). Zero on inactive
    // lanes so their h stays exactly 0 (they cover the hb[51..63] pad).
    float ww[4], bb[4];
#pragma unroll
    for (int g = 0; g < 4; ++g) {
        const int row = m + g * HIDDEN;
        ww[g] = active ? W_w[row] : 0.f;
        bb[g] = active ? (W_b[row] + U_b[row]) : 0.f;
    }
    const float lw = active ? lin_w[m] : 0.f;
    const float lb = lin_b[0];

    // U columns for this wave: k = wid*NK + j, j in [0, NK). Column 51 (only
    // reachable by wave1's j=25) is zero-padded; hb[51] is also 0.
    float U[NK][4];
#pragma unroll
    for (int j = 0; j < NK; ++j) {
        const int k = wid * NK + j;
#pragma unroll
        for (int g = 0; g < 4; ++g) {
            const int row = m + g * HIDDEN;
            U[j][g] = (active && k < HIDDEN) ? U_w[row * HIDDEN + k] : 0.f;
        }
    }

    float h = 0.f, c = 0.f, red = 0.f;
    const float* __restrict__ xrow = x + (long)b * LSEQ;
    float* __restrict__ orow = out + (long)b * LSEQ;

    // Prime the h broadcast buffer with h0 = 0.
    if (wid == 0) hb[lane] = 0.f;
    __syncthreads();

    float x_cur = xrow[0];  // wave-uniform scalar load
    for (int t = 0; t < LSEQ; ++t) {
        const int tn = (t + 1 < LSEQ) ? (t + 1) : t;
        float x_next = xrow[tn];

        // Broadcast-load h_{t-1} for this wave's k-range: 7 x ds_read_b128.
        // wave0 reads floats [0..27] (uses 0..25), wave1 [24..51] (uses 26..51).
        float hq[28];
#pragma unroll
        for (int q = 0; q < 7; ++q) {
            float4 v = *(const float4*)&hb[wid * 24 + q * 4];
            hq[q * 4 + 0] = v.x; hq[q * 4 + 1] = v.y;
            hq[q * 4 + 2] = v.z; hq[q * 4 + 3] = v.w;
        }

        // Pipelined butterfly for the PREVIOUS step's output (red holds
        // h_{t-1} * lw). Unconditional on both waves so the scheduler can
        // interleave the swizzles with the FMA block; only wave1 stores.
        float r = red;
#pragma unroll
        for (int off = 32; off > 0; off >>= 1)
            r += __shfl_xor(r, off, 64);

        // Partial gates. Both waves fold in the x-term; wave1's ww/bb... no:
        // only wave0 carries ww/bb so the x/bias term is counted once.
        float p0, p1, p2, p3;
        if (wid == 0) {
            p0 = fmaf(x_cur, ww[0], bb[0]);
            p1 = fmaf(x_cur, ww[1], bb[1]);
            p2 = fmaf(x_cur, ww[2], bb[2]);
            p3 = fmaf(x_cur, ww[3], bb[3]);
        } else {
            p0 = p1 = p2 = p3 = 0.f;
        }

#pragma unroll
        for (int j = 0; j < NK; ++j) {
            // word index: k - wid*24 = j + 2*wid (constant per wave)
            const float hk = hq[j + 2 * wid];
            p0 = fmaf(hk, U[j][0], p0);
            p1 = fmaf(hk, U[j][1], p1);
            p2 = fmaf(hk, U[j][2], p2);
            p3 = fmaf(hk, U[j][3], p3);
        }

        // Store previous step's output (wave1 lane0), off the critical path.
        const int ot = (t > 0) ? (t - 1) : 0;
        if (tid == 64) orow[ot] = r + lb;

        // Exchange partials (one b128 each way).
        *(float4*)&pg[wid][lane][0] = make_float4(p0, p1, p2, p3);
        __syncthreads();
        float4 po = *(const float4*)&pg[1 - wid][lane][0];

        // Full gates -- own + other commutes exactly, so both waves hold
        // bitwise-identical state.
        const float gi = p0 + po.x;
        const float gf = p1 + po.y;
        const float gg = p2 + po.z;
        const float go = p3 + po.w;

        // NOTE: faithful to reference -- no sigmoid on gates.
        c = fmaf(gf, c, gi * gg);
        const float th = fast_tanh(c);
        h = go * th;
        red = h * lw;

        if (wid == 0) hb[lane] = h;   // lanes >= 51 write exact 0 (pad)
        __syncthreads();

        x_cur = x_next;
    }

    // Drain: output for t = LSEQ-1.
#pragma unroll
    for (int off = 32; off > 0; off >>= 1)
        red += __shfl_xor(red, off, 64);
    if (tid == 64) orow[LSEQ - 1] = red + lb;
}

extern "C" void kernel_launch(void* const* d_in, const int* in_sizes, int n_in,
                              void* d_out, int out_size, void* d_ws, size_t ws_size,
                              hipStream_t stream) {
    const float* x     = (const float*)d_in[0];
    const float* W_w   = (const float*)d_in[1];
    const float* W_b   = (const float*)d_in[2];
    const float* U_w   = (const float*)d_in[3];
    const float* U_b   = (const float*)d_in[4];
    const float* lin_w = (const float*)d_in[5];
    const float* lin_b = (const float*)d_in[6];
    // d_in[7] = future (static 0; out_size == B*LSEQ)
    float* out = (float*)d_out;

    const int B = in_sizes[0] / LSEQ;  // 1024
    lstm_seq_kernel<<<dim3(B), dim3(128), 0, stream>>>(
        x, W_w, W_b, U_w, U_b, lin_w, lin_b, out);
}

// Round 4
// 691.393 us; speedup vs baseline: 7.9697x; 7.9697x over previous
//
#include <hip/hip_runtime.h>

#define HIDDEN 51
#define LSEQ 1000
#define NK 26   // k-columns per wave: wave0 k=0..25, wave1 k=26..51 (51 = zero pad)

// Branch-free tanh: tanh(v) = 1 - 2/(exp2(2*log2e*v)+1). Saturates to +/-1.
__device__ __forceinline__ float fast_tanh(float v) {
    float e = __builtin_amdgcn_exp2f(v * 2.885390081777927f);  // 2*log2(e)
    float r = __builtin_amdgcn_rcpf(e + 1.0f);
    return fmaf(-2.0f, r, 1.0f);
}

// Two waves per batch element, k-split. Each wave holds 26 cols x 4 gate rows
// of U in VGPRs (104 regs, no AGPR tax). Both waves compute bitwise-identical
// c/h (gate sum = own+other, float add commutes), so each wave keeps a PRIVATE
// h-broadcast buffer -> no barrier needed for h. Partial-gate exchange is one
// b128 LDS round-trip through a parity-double-buffered slab -> exactly ONE
// __syncthreads per step. All register-array indices are compile-time
// constants (R3 lesson: a runtime index component sent hq[] to scratch, 8x).
__global__ __launch_bounds__(128, 2) void lstm_seq_kernel(
    const float* __restrict__ x,
    const float* __restrict__ W_w,
    const float* __restrict__ W_b,
    const float* __restrict__ U_w,
    const float* __restrict__ U_b,
    const float* __restrict__ lin_w,
    const float* __restrict__ lin_b,
    float* __restrict__ out)
{
    __shared__ float hbw[2][64];         // per-WAVE private h broadcast
    __shared__ float pg[2][2][64][4];    // [t&1][wid][lane][gate] exchange

    const int b    = blockIdx.x;
    const int tid  = threadIdx.x;
    const int wid  = tid >> 6;           // 0 or 1
    const int lane = tid & 63;
    const bool active = lane < HIDDEN;   // lanes 51..63 produce exact zeros
    const int m = active ? lane : 0;

    // x-projection + fused bias (counted once: wave0 only).
    float ww[4], bb[4];
#pragma unroll
    for (int g = 0; g < 4; ++g) {
        const int row = m + g * HIDDEN;
        ww[g] = (active && wid == 0) ? W_w[row] : 0.f;
        bb[g] = (active && wid == 0) ? (W_b[row] + U_b[row]) : 0.f;
    }
    const float lw = active ? lin_w[m] : 0.f;
    const float lb = lin_b[0];

    // U columns for this wave: k = wid*NK + j. k==51 zero-padded.
    float U[NK][4];
#pragma unroll
    for (int j = 0; j < NK; ++j) {
        const int k = wid * NK + j;
#pragma unroll
        for (int g = 0; g < 4; ++g) {
            const int row = m + g * HIDDEN;
            U[j][g] = (active && k < HIDDEN) ? U_w[row * HIDDEN + k] : 0.f;
        }
    }

    float h = 0.f, c = 0.f, red = 0.f;
    const float* __restrict__ xrow = x + (long)b * LSEQ;
    float* __restrict__ orow = out + (long)b * LSEQ;

    // Each wave zeroes its OWN h buffer -- no barrier needed (private).
    hbw[wid][lane] = 0.f;
    // Runtime base address (legal); register-array indices stay constant.
    const float* __restrict__ hsrc = &hbw[wid][wid * NK];

    float x_cur = xrow[0];  // wave-uniform scalar load
    for (int t = 0; t < LSEQ; ++t) {
        const int tn = (t + 1 < LSEQ) ? (t + 1) : t;
        float x_next = xrow[tn];
        const int par = t & 1;

        // Broadcast-load this wave's h_k range from its private buffer.
        // Same-address across lanes -> LDS broadcast, conflict-free.
        float hq[NK];
#pragma unroll
        for (int j = 0; j < NK; ++j) hq[j] = hsrc[j];

        // Pipelined butterfly for the PREVIOUS step's output.
        float r = red;
#pragma unroll
        for (int off = 32; off > 0; off >>= 1)
            r += __shfl_xor(r, off, 64);

        // Partial gates (x-term folded via ww/bb which are zero on wave1).
        float p0 = fmaf(x_cur, ww[0], bb[0]);
        float p1 = fmaf(x_cur, ww[1], bb[1]);
        float p2 = fmaf(x_cur, ww[2], bb[2]);
        float p3 = fmaf(x_cur, ww[3], bb[3]);

#pragma unroll
        for (int j = 0; j < NK; ++j) {
            const float hk = hq[j];
            p0 = fmaf(hk, U[j][0], p0);
            p1 = fmaf(hk, U[j][1], p1);
            p2 = fmaf(hk, U[j][2], p2);
            p3 = fmaf(hk, U[j][3], p3);
        }

        // Store previous step's output (wave1 lane0), off the critical path.
        const int ot = (t > 0) ? (t - 1) : 0;
        if (tid == 64) orow[ot] = r + lb;

        // Exchange partials: one b128 each way, ONE barrier. Parity
        // double-buffering makes the write at t+2 safe vs the read at t.
        *(float4*)&pg[par][wid][lane][0] = make_float4(p0, p1, p2, p3);
        __syncthreads();
        const float4 po = *(const float4*)&pg[par][1 - wid][lane][0];

        // own + other commutes exactly -> bitwise-identical on both waves.
        const float gi = p0 + po.x;
        const float gf = p1 + po.y;
        const float gg = p2 + po.z;
        const float go = p3 + po.w;

        // NOTE: faithful to reference -- no sigmoid on gates.
        c = fmaf(gf, c, gi * gg);
        const float th = fast_tanh(c);
        h = go * th;
        red = h * lw;

        hbw[wid][lane] = h;   // private buffer: wave-internal lgkmcnt ordering
                              // suffices, no barrier. Lanes >= 51 write 0.
        x_cur = x_next;
    }

    // Drain: output for t = LSEQ-1.
#pragma unroll
    for (int off = 32; off > 0; off >>= 1)
        red += __shfl_xor(red, off, 64);
    if (tid == 64) orow[LSEQ - 1] = red + lb;
}

extern "C" void kernel_launch(void* const* d_in, const int* in_sizes, int n_in,
                              void* d_out, int out_size, void* d_ws, size_t ws_size,
                              hipStream_t stream) {
    const float* x     = (const float*)d_in[0];
    const float* W_w   = (const float*)d_in[1];
    const float* W_b   = (const float*)d_in[2];
    const float* U_w   = (const float*)d_in[3];
    const float* U_b   = (const float*)d_in[4];
    const float* lin_w = (const float*)d_in[5];
    const float* lin_b = (const float*)d_in[6];
    // d_in[7] = future (static 0; out_size == B*LSEQ)
    float* out = (float*)d_out;

    const int B = in_sizes[0] / LSEQ;  // 1024
    lstm_seq_kernel<<<dim3(B), dim3(128), 0, stream>>>(
        x, W_w, W_b, U_w, U_b, lin_w, lin_b, out);
}